// Round 1
// baseline (440.642 us; speedup 1.0000x reference)
//
#include <hip/hip_runtime.h>
#include <hip/hip_bf16.h>

// out[i] = exp(s) * x[i]  — elementwise, memory-bound.
// x: 65536*1024 fp32; s: 1 fp32. Vectorized float4, grid-stride loop.

__global__ void __launch_bounds__(256) spherical_scale_kernel(
    const float4* __restrict__ x, const float* __restrict__ s,
    float4* __restrict__ out, long long n4) {
    const float scale = __expf(0.0f) * expf(s[0]);  // expf(s[0]); __expf(0)=1 keeps precision path simple
    long long i = (long long)blockIdx.x * blockDim.x + threadIdx.x;
    long long stride = (long long)gridDim.x * blockDim.x;
    for (; i < n4; i += stride) {
        float4 v = x[i];
        v.x *= scale; v.y *= scale; v.z *= scale; v.w *= scale;
        out[i] = v;
    }
}

extern "C" void kernel_launch(void* const* d_in, const int* in_sizes, int n_in,
                              void* d_out, int out_size, void* d_ws, size_t ws_size,
                              hipStream_t stream) {
    const float* x = (const float*)d_in[0];
    const float* s = (const float*)d_in[1];
    float* out = (float*)d_out;

    long long n = (long long)in_sizes[0];   // 65536*1024, divisible by 4
    long long n4 = n / 4;

    int block = 256;
    long long blocks_needed = (n4 + block - 1) / block;
    int grid = (int)(blocks_needed < 2048 ? blocks_needed : 2048);

    spherical_scale_kernel<<<grid, block, 0, stream>>>(
        (const float4*)x, s, (float4*)out, n4);
}